// Round 1
// baseline (10552.438 us; speedup 1.0000x reference)
//
#include <hip/hip_runtime.h>
#include <math.h>

// FusionRestormerBlock fp32 baseline.
// Layout: tokenized buffers (row r = wid*64 + l, l = hi*8+wi, 192 ch contiguous).
// A = cln scratch, B = x1/x2 scratch (each 25165824 floats in d_ws).
// All kernels: 1 block per window (2048 blocks), 256 threads, LDS < 58KB.

#define TPB 256
#define NWIN 2048
#define SCALEF 0.20412414523193154f  // 24^-0.5

__device__ __forceinline__ float gelu_f(float x) {
    return 0.5f * x * (1.0f + erff(x * 0.70710678118654752f));
}

// ---------------- K1: gather + conditional LayerNorm (ln1) -> A ----------------
__global__ __launch_bounds__(TPB) void k1_prep(
    const float* __restrict__ xrgb, const float* __restrict__ gamma, const float* __restrict__ beta,
    const float* __restrict__ ln1w, const float* __restrict__ ln1b, float* __restrict__ A)
{
    __shared__ float s_x[64 * 193];
    __shared__ float s_mu[64], s_rs[64];
    const int tid = threadIdx.x;
    const int wid = blockIdx.x;
    const int b = wid >> 8, hb = (wid >> 4) & 15, wb = wid & 15;
    const int xbase = ((b * 192) << 14) + ((hb * 8) << 7) + wb * 8;
    const int arow0 = wid * 12288;

    for (int idx = tid; idx < 12288; idx += TPB) {
        int c = idx >> 6, l = idx & 63;
        s_x[l * 193 + c] = xrgb[xbase + (c << 14) + ((l >> 3) << 7) + (l & 7)];
    }
    __syncthreads();
    {
        int t = tid >> 2, q4 = tid & 3;
        float sum = 0.f, sq = 0.f;
        for (int j = 0; j < 48; j++) {
            float v = s_x[t * 193 + q4 * 48 + j];
            sum += v; sq += v * v;
        }
        sum += __shfl_xor(sum, 1); sum += __shfl_xor(sum, 2);
        sq  += __shfl_xor(sq, 1);  sq  += __shfl_xor(sq, 2);
        float mu = sum * (1.f / 192.f);
        float var = sq * (1.f / 192.f) - mu * mu;
        if (q4 == 0) { s_mu[t] = mu; s_rs[t] = rsqrtf(var + 1e-6f); }
    }
    __syncthreads();
    for (int idx = tid; idx < 12288; idx += TPB) {
        int t = idx / 192, c = idx - t * 192;
        float xn = (s_x[t * 193 + c] - s_mu[t]) * s_rs[t];
        A[arow0 + idx] = (xn * ln1w[c] + ln1b[c]) * gamma[b * 192 + c] + beta[b * 192 + c];
    }
}

// ---------------- K2: window self-attention + rel bias + proj + residual + cln1 ----------------
// reads A (cln1(x_rgb)), x_rgb; writes B = x1, A = cln1(x1)
__global__ __launch_bounds__(TPB) void k2_self(
    float* __restrict__ A, const float* __restrict__ xrgb,
    const float* __restrict__ qkvw, const float* __restrict__ qkvb,
    const float* __restrict__ apw, const float* __restrict__ apb,
    const float* __restrict__ relb,
    const float* __restrict__ ln1w, const float* __restrict__ ln1b,
    const float* __restrict__ gamma, const float* __restrict__ beta,
    float* __restrict__ Bout)
{
    __shared__ float s_u[12352];
    __shared__ float s_rb[1800];
    __shared__ float s_mu[64], s_rs[64];
    float* s_q  = s_u;          // 64 x 25 (also O after S-phase)
    float* s_k  = s_u + 1600;   // 64 x 25
    float* s_v  = s_u + 3200;   // 64 x 25
    float* s_at = s_u + 4800;   // 64 x 17  (A k-tile)
    float* s_wt = s_u + 5888;   // 16 x 76  (W k-tile, transposed)
    float* s_pw = s_u + 7104;   // P (stride 73) / WP^T (24 x 196), 4704 floats
    float* s_x2 = s_u;          // 64 x 193 (epilogue, overlays everything)

    const int tid = threadIdx.x;
    const int wid = blockIdx.x;
    const int b = wid >> 8, hb = (wid >> 4) & 15, wb = wid & 15;
    const int xbase = ((b * 192) << 14) + ((hb * 8) << 7) + wb * 8;
    const int arow0 = wid * 12288;

    for (int i = tid; i < 1800; i += TPB) s_rb[i] = relb[i];

    const int yt0 = (tid >> 4) * 4;       // y acc: 4 tokens
    const int yo0 = (tid & 15) * 12;      // x 12 out channels
    float y[48];
#pragma unroll
    for (int i = 0; i < 48; i++) y[i] = 0.f;

    const int tg  = (tid >> 3) * 2;       // QKV gemm: 2 tokens
    const int wg  = (tid & 7) * 9;        // x 9 of 72 rows
    const int sq0 = (tid >> 4) * 4, sk0 = (tid & 15) * 4;  // S: 4x4
    const int ot0 = (tid >> 3) * 2, od0 = (tid & 7) * 3;   // O: 2 tok x 3 dim

    for (int h = 0; h < 8; h++) {
        // ---- QKV = A_win @ W_h^T (+bias), tiled over k ----
        float acc[18];
#pragma unroll
        for (int i = 0; i < 18; i++) acc[i] = 0.f;
        for (int kt = 0; kt < 12; kt++) {
            __syncthreads();
            for (int idx = tid; idx < 1024; idx += TPB) {
                int t = idx >> 4, kk = idx & 15;
                s_at[t * 17 + kk] = A[arow0 + t * 192 + kt * 16 + kk];
            }
            for (int idx = tid; idx < 1152; idx += TPB) {
                int r = idx >> 4, kk = idx & 15;
                int gr = (r < 24) ? (h * 24 + r) : (r < 48) ? (168 + h * 24 + r) : (336 + h * 24 + r);
                s_wt[kk * 76 + r] = qkvw[gr * 192 + kt * 16 + kk];
            }
            __syncthreads();
#pragma unroll
            for (int kk = 0; kk < 16; kk++) {
                float a0 = s_at[tg * 17 + kk];
                float a1 = s_at[tg * 17 + 17 + kk];
#pragma unroll
                for (int j = 0; j < 9; j++) {
                    float w = s_wt[kk * 76 + wg + j];
                    acc[j]     += a0 * w;
                    acc[9 + j] += a1 * w;
                }
            }
        }
        __syncthreads();
#pragma unroll
        for (int j = 0; j < 9; j++) {
            int r = wg + j;
            int gr = (r < 24) ? (h * 24 + r) : (r < 48) ? (168 + h * 24 + r) : (336 + h * 24 + r);
            float bias = qkvb[gr];
            float* dst; int d;
            if (r < 24)      { dst = s_q; d = r; }
            else if (r < 48) { dst = s_k; d = r - 24; }
            else             { dst = s_v; d = r - 48; }
            dst[tg * 25 + d]       = acc[j] + bias;
            dst[(tg + 1) * 25 + d] = acc[9 + j] + bias;
        }
        __syncthreads();
        // ---- S = Q K^T * scale + rel_bias ----
        {
            float s[16];
#pragma unroll
            for (int i = 0; i < 16; i++) s[i] = 0.f;
            for (int c = 0; c < 24; c++) {
                float qv[4], kv[4];
#pragma unroll
                for (int i = 0; i < 4; i++) { qv[i] = s_q[(sq0 + i) * 25 + c]; kv[i] = s_k[(sk0 + i) * 25 + c]; }
#pragma unroll
                for (int i = 0; i < 4; i++)
#pragma unroll
                    for (int j = 0; j < 4; j++) s[i * 4 + j] += qv[i] * kv[j];
            }
#pragma unroll
            for (int i = 0; i < 4; i++) {
                int q = sq0 + i, qi = q >> 3, qj = q & 7;
#pragma unroll
                for (int j = 0; j < 4; j++) {
                    int k = sk0 + j, ki = k >> 3, kj = k & 7;
                    int ridx = (qi - ki + 7) * 15 + (qj - kj + 7);
                    s_pw[q * 73 + k] = s[i * 4 + j] * SCALEF + s_rb[ridx * 8 + h];
                }
            }
        }
        __syncthreads();
        // ---- row softmax (4 lanes per row) ----
        {
            int r = tid >> 2, q4 = tid & 3;
            float m = -1e30f;
#pragma unroll
            for (int j = 0; j < 16; j++) m = fmaxf(m, s_pw[r * 73 + q4 * 16 + j]);
            m = fmaxf(m, __shfl_xor(m, 1));
            m = fmaxf(m, __shfl_xor(m, 2));
            float e[16]; float sum = 0.f;
#pragma unroll
            for (int j = 0; j < 16; j++) { e[j] = __expf(s_pw[r * 73 + q4 * 16 + j] - m); sum += e[j]; }
            sum += __shfl_xor(sum, 1);
            sum += __shfl_xor(sum, 2);
            float inv = 1.f / sum;
#pragma unroll
            for (int j = 0; j < 16; j++) s_pw[r * 73 + q4 * 16 + j] = e[j] * inv;
        }
        __syncthreads();
        // ---- O = P V (write into s_q region) ----
        {
            float o[6] = {0.f, 0.f, 0.f, 0.f, 0.f, 0.f};
            for (int k = 0; k < 64; k++) {
                float p0 = s_pw[ot0 * 73 + k], p1 = s_pw[ot0 * 73 + 73 + k];
#pragma unroll
                for (int j = 0; j < 3; j++) {
                    float vv = s_v[k * 25 + od0 + j];
                    o[j]     += p0 * vv;
                    o[3 + j] += p1 * vv;
                }
            }
#pragma unroll
            for (int j = 0; j < 3; j++) {
                s_q[ot0 * 25 + od0 + j]      = o[j];
                s_q[ot0 * 25 + 25 + od0 + j] = o[3 + j];
            }
        }
        __syncthreads();
        // ---- stage WP^T (attn_proj slice for head h) over s_pw ----
        for (int idx = tid; idx < 4608; idx += TPB) {
            int o = idx / 24, d = idx - o * 24;
            s_pw[d * 196 + o] = apw[o * 192 + h * 24 + d];
        }
        __syncthreads();
        // ---- y += O @ WP^T ----
        for (int d = 0; d < 24; d++) {
            float ov[4];
#pragma unroll
            for (int i = 0; i < 4; i++) ov[i] = s_q[(yt0 + i) * 25 + d];
#pragma unroll
            for (int j = 0; j < 12; j++) {
                float w = s_pw[d * 196 + yo0 + j];
#pragma unroll
                for (int i = 0; i < 4; i++) y[i * 12 + j] += ov[i] * w;
            }
        }
        __syncthreads();
    }
    // ---- epilogue: x1 = x_rgb + y + bias ; write B=x1, A=cln1(x1) ----
    for (int idx = tid; idx < 12288; idx += TPB) {
        int c = idx >> 6, l = idx & 63;
        s_x2[l * 193 + c] = xrgb[xbase + (c << 14) + ((l >> 3) << 7) + (l & 7)];
    }
    __syncthreads();
#pragma unroll
    for (int i = 0; i < 4; i++)
#pragma unroll
        for (int j = 0; j < 12; j++) {
            int o = yo0 + j;
            s_x2[(yt0 + i) * 193 + o] += y[i * 12 + j] + apb[o];
        }
    __syncthreads();
    {
        int t = tid >> 2, q4 = tid & 3;
        float sum = 0.f, sq = 0.f;
        for (int j = 0; j < 48; j++) {
            float v = s_x2[t * 193 + q4 * 48 + j];
            sum += v; sq += v * v;
        }
        sum += __shfl_xor(sum, 1); sum += __shfl_xor(sum, 2);
        sq  += __shfl_xor(sq, 1);  sq  += __shfl_xor(sq, 2);
        float mu = sum * (1.f / 192.f);
        float var = sq * (1.f / 192.f) - mu * mu;
        if (q4 == 0) { s_mu[t] = mu; s_rs[t] = rsqrtf(var + 1e-6f); }
    }
    __syncthreads();
    for (int idx = tid; idx < 12288; idx += TPB) {
        int t = idx / 192, c = idx - t * 192;
        float v = s_x2[t * 193 + c];
        Bout[arow0 + idx] = v;
        float xn = (v - s_mu[t]) * s_rs[t];
        A[arow0 + idx] = (xn * ln1w[c] + ln1b[c]) * gamma[b * 192 + c] + beta[b * 192 + c];
    }
}

// ---------------- K3: windowed cross-attention + proj + residual + cln2 ----------------
// reads A (cln1(x1)), x_sar, B (x1); writes B = x2, A = cln2(x2)
__global__ __launch_bounds__(TPB) void k3_cross(
    float* __restrict__ A, const float* __restrict__ xsar,
    const float* __restrict__ qw, const float* __restrict__ kvw,
    const float* __restrict__ cpw, const float* __restrict__ cpb,
    const float* __restrict__ ln2w, const float* __restrict__ ln2b,
    const float* __restrict__ gamma, const float* __restrict__ beta,
    float* __restrict__ Bbuf)
{
    __shared__ float s_u[12896];
    __shared__ float s_mu[64], s_rs[64];
    float* s_q  = s_u;          // 64 x 25 (O after S)
    float* s_k  = s_u + 1600;
    float* s_v  = s_u + 3200;
    float* s_at = s_u + 4800;   // A k-tile (q source)
    float* s_st = s_u + 5888;   // x_sar k-tile (kv source)
    float* s_wt = s_u + 6976;   // 16 x 76
    float* s_pw = s_u + 8192;   // P / WP^T
    float* s_x2 = s_u;

    const int tid = threadIdx.x;
    const int wid = blockIdx.x;
    const int b = wid >> 8, hb = (wid >> 4) & 15, wb = wid & 15;
    const int xbase = ((b * 192) << 14) + ((hb * 8) << 7) + wb * 8;
    const int arow0 = wid * 12288;

    const int yt0 = (tid >> 4) * 4;
    const int yo0 = (tid & 15) * 12;
    float y[48];
#pragma unroll
    for (int i = 0; i < 48; i++) y[i] = 0.f;

    const int tg  = (tid >> 3) * 2;
    const int wg  = (tid & 7) * 9;
    const int sq0 = (tid >> 4) * 4, sk0 = (tid & 15) * 4;
    const int ot0 = (tid >> 3) * 2, od0 = (tid & 7) * 3;

    for (int h = 0; h < 8; h++) {
        float acc[18];
#pragma unroll
        for (int i = 0; i < 18; i++) acc[i] = 0.f;
        for (int kt = 0; kt < 12; kt++) {
            __syncthreads();
            for (int idx = tid; idx < 1024; idx += TPB) {
                int t = idx >> 4, kk = idx & 15;
                s_at[t * 17 + kk] = A[arow0 + t * 192 + kt * 16 + kk];
            }
            for (int idx = tid; idx < 1024; idx += TPB) {
                int kk = idx >> 6, l = idx & 63;
                s_st[l * 17 + kk] = xsar[xbase + ((kt * 16 + kk) << 14) + ((l >> 3) << 7) + (l & 7)];
            }
            for (int idx = tid; idx < 1152; idx += TPB) {
                int r = idx >> 4, kk = idx & 15;
                const float* wsrc; int gr;
                if (r < 24)      { wsrc = qw;  gr = h * 24 + r; }
                else if (r < 48) { wsrc = kvw; gr = h * 24 + r - 24; }
                else             { wsrc = kvw; gr = 192 + h * 24 + r - 48; }
                s_wt[kk * 76 + r] = wsrc[gr * 192 + kt * 16 + kk];
            }
            __syncthreads();
#pragma unroll
            for (int kk = 0; kk < 16; kk++) {
                float aq0 = s_at[tg * 17 + kk], aq1 = s_at[tg * 17 + 17 + kk];
                float as0 = s_st[tg * 17 + kk], as1 = s_st[tg * 17 + 17 + kk];
#pragma unroll
                for (int j = 0; j < 9; j++) {
                    float w = s_wt[kk * 76 + wg + j];
                    bool isq = (wg + j) < 24;
                    acc[j]     += (isq ? aq0 : as0) * w;
                    acc[9 + j] += (isq ? aq1 : as1) * w;
                }
            }
        }
        __syncthreads();
#pragma unroll
        for (int j = 0; j < 9; j++) {
            int r = wg + j;
            float* dst; int d;
            if (r < 24)      { dst = s_q; d = r; }
            else if (r < 48) { dst = s_k; d = r - 24; }
            else             { dst = s_v; d = r - 48; }
            dst[tg * 25 + d]       = acc[j];
            dst[(tg + 1) * 25 + d] = acc[9 + j];
        }
        __syncthreads();
        {
            float s[16];
#pragma unroll
            for (int i = 0; i < 16; i++) s[i] = 0.f;
            for (int c = 0; c < 24; c++) {
                float qv[4], kv[4];
#pragma unroll
                for (int i = 0; i < 4; i++) { qv[i] = s_q[(sq0 + i) * 25 + c]; kv[i] = s_k[(sk0 + i) * 25 + c]; }
#pragma unroll
                for (int i = 0; i < 4; i++)
#pragma unroll
                    for (int j = 0; j < 4; j++) s[i * 4 + j] += qv[i] * kv[j];
            }
#pragma unroll
            for (int i = 0; i < 4; i++)
#pragma unroll
                for (int j = 0; j < 4; j++)
                    s_pw[(sq0 + i) * 73 + sk0 + j] = s[i * 4 + j] * SCALEF;
        }
        __syncthreads();
        {
            int r = tid >> 2, q4 = tid & 3;
            float m = -1e30f;
#pragma unroll
            for (int j = 0; j < 16; j++) m = fmaxf(m, s_pw[r * 73 + q4 * 16 + j]);
            m = fmaxf(m, __shfl_xor(m, 1));
            m = fmaxf(m, __shfl_xor(m, 2));
            float e[16]; float sum = 0.f;
#pragma unroll
            for (int j = 0; j < 16; j++) { e[j] = __expf(s_pw[r * 73 + q4 * 16 + j] - m); sum += e[j]; }
            sum += __shfl_xor(sum, 1);
            sum += __shfl_xor(sum, 2);
            float inv = 1.f / sum;
#pragma unroll
            for (int j = 0; j < 16; j++) s_pw[r * 73 + q4 * 16 + j] = e[j] * inv;
        }
        __syncthreads();
        {
            float o[6] = {0.f, 0.f, 0.f, 0.f, 0.f, 0.f};
            for (int k = 0; k < 64; k++) {
                float p0 = s_pw[ot0 * 73 + k], p1 = s_pw[ot0 * 73 + 73 + k];
#pragma unroll
                for (int j = 0; j < 3; j++) {
                    float vv = s_v[k * 25 + od0 + j];
                    o[j]     += p0 * vv;
                    o[3 + j] += p1 * vv;
                }
            }
#pragma unroll
            for (int j = 0; j < 3; j++) {
                s_q[ot0 * 25 + od0 + j]      = o[j];
                s_q[ot0 * 25 + 25 + od0 + j] = o[3 + j];
            }
        }
        __syncthreads();
        for (int idx = tid; idx < 4608; idx += TPB) {
            int o = idx / 24, d = idx - o * 24;
            s_pw[d * 196 + o] = cpw[o * 192 + h * 24 + d];
        }
        __syncthreads();
        for (int d = 0; d < 24; d++) {
            float ov[4];
#pragma unroll
            for (int i = 0; i < 4; i++) ov[i] = s_q[(yt0 + i) * 25 + d];
#pragma unroll
            for (int j = 0; j < 12; j++) {
                float w = s_pw[d * 196 + yo0 + j];
#pragma unroll
                for (int i = 0; i < 4; i++) y[i * 12 + j] += ov[i] * w;
            }
        }
        __syncthreads();
    }
    // ---- epilogue: x2 = x1 + y + bias ; write B=x2, A=cln2(x2) ----
    for (int idx = tid; idx < 12288; idx += TPB) {
        int t = idx / 192, c = idx - t * 192;
        s_x2[t * 193 + c] = Bbuf[arow0 + idx];
    }
    __syncthreads();
#pragma unroll
    for (int i = 0; i < 4; i++)
#pragma unroll
        for (int j = 0; j < 12; j++) {
            int o = yo0 + j;
            s_x2[(yt0 + i) * 193 + o] += y[i * 12 + j] + cpb[o];
        }
    __syncthreads();
    {
        int t = tid >> 2, q4 = tid & 3;
        float sum = 0.f, sq = 0.f;
        for (int j = 0; j < 48; j++) {
            float v = s_x2[t * 193 + q4 * 48 + j];
            sum += v; sq += v * v;
        }
        sum += __shfl_xor(sum, 1); sum += __shfl_xor(sum, 2);
        sq  += __shfl_xor(sq, 1);  sq  += __shfl_xor(sq, 2);
        float mu = sum * (1.f / 192.f);
        float var = sq * (1.f / 192.f) - mu * mu;
        if (q4 == 0) { s_mu[t] = mu; s_rs[t] = rsqrtf(var + 1e-6f); }
    }
    __syncthreads();
    for (int idx = tid; idx < 12288; idx += TPB) {
        int t = idx / 192, c = idx - t * 192;
        float v = s_x2[t * 193 + c];
        Bbuf[arow0 + idx] = v;
        float xn = (v - s_mu[t]) * s_rs[t];
        A[arow0 + idx] = (xn * ln2w[c] + ln2b[c]) * gamma[b * 192 + c] + beta[b * 192 + c];
    }
}

// ---------------- K4: FFN (conv1x1 -> GELU -> conv1x1) + residual, scatter to NCHW ----------------
__global__ __launch_bounds__(TPB) void k4_ffn(
    const float* __restrict__ A, const float* __restrict__ Bin,
    const float* __restrict__ w1, const float* __restrict__ w2,
    float* __restrict__ out)
{
    __shared__ float s_u[12560];
    float* s_h  = s_u;           // 64 x 131 hidden chunk
    float* s_at = s_u + 8384;    // 64 x 17
    float* s_w  = s_u + 9472;    // w1 tile 16x129 / w2 tile 16x193
    float* s_out = s_u;          // 64 x 193 epilogue

    const int tid = threadIdx.x;
    const int wid = blockIdx.x;
    const int b = wid >> 8, hb = (wid >> 4) & 15, wb = wid & 15;
    const int xbase = ((b * 192) << 14) + ((hb * 8) << 7) + wb * 8;
    const int arow0 = wid * 12288;

    const int yt0 = (tid >> 4) * 4;
    const int yo0 = (tid & 15) * 12;
    const int th0 = (tid >> 5) * 8;
    const int fl  = tid & 31;        // hidden f = fl + 32*j

    float y[48];
#pragma unroll
    for (int i = 0; i < 48; i++) y[i] = 0.f;

    for (int chunk = 0; chunk < 6; chunk++) {
        float hacc[32];
#pragma unroll
        for (int i = 0; i < 32; i++) hacc[i] = 0.f;
        for (int kt = 0; kt < 12; kt++) {
            __syncthreads();
            for (int idx = tid; idx < 1024; idx += TPB) {
                int t = idx >> 4, kk = idx & 15;
                s_at[t * 17 + kk] = A[arow0 + t * 192 + kt * 16 + kk];
            }
            for (int idx = tid; idx < 2048; idx += TPB) {
                int f = idx >> 4, kk = idx & 15;
                s_w[kk * 129 + f] = w1[(chunk * 128 + f) * 192 + kt * 16 + kk];
            }
            __syncthreads();
#pragma unroll
            for (int kk = 0; kk < 16; kk++) {
                float a[8];
#pragma unroll
                for (int i = 0; i < 8; i++) a[i] = s_at[(th0 + i) * 17 + kk];
#pragma unroll
                for (int j = 0; j < 4; j++) {
                    float w = s_w[kk * 129 + fl + 32 * j];
#pragma unroll
                    for (int i = 0; i < 8; i++) hacc[i * 4 + j] += a[i] * w;
                }
            }
        }
        __syncthreads();
#pragma unroll
        for (int i = 0; i < 8; i++)
#pragma unroll
            for (int j = 0; j < 4; j++)
                s_h[(th0 + i) * 131 + fl + 32 * j] = gelu_f(hacc[i * 4 + j]);
        for (int ft = 0; ft < 8; ft++) {
            __syncthreads();
            for (int idx = tid; idx < 3072; idx += TPB) {
                int o = idx >> 4, ff = idx & 15;
                s_w[ff * 193 + o] = w2[o * 768 + chunk * 128 + ft * 16 + ff];
            }
            __syncthreads();
#pragma unroll
            for (int ff = 0; ff < 16; ff++) {
                float hv[4];
#pragma unroll
                for (int i = 0; i < 4; i++) hv[i] = s_h[(yt0 + i) * 131 + ft * 16 + ff];
#pragma unroll
                for (int j = 0; j < 12; j++) {
                    float w = s_w[ff * 193 + yo0 + j];
#pragma unroll
                    for (int i = 0; i < 4; i++) y[i * 12 + j] += hv[i] * w;
                }
            }
        }
    }
    __syncthreads();
#pragma unroll
    for (int i = 0; i < 4; i++)
#pragma unroll
        for (int j = 0; j < 12; j++)
            y[i * 12 + j] += Bin[arow0 + (yt0 + i) * 192 + yo0 + j];
#pragma unroll
    for (int i = 0; i < 4; i++)
#pragma unroll
        for (int j = 0; j < 12; j++)
            s_out[(yt0 + i) * 193 + yo0 + j] = y[i * 12 + j];
    __syncthreads();
    for (int idx = tid; idx < 12288; idx += TPB) {
        int c = idx >> 6, l = idx & 63;
        out[xbase + (c << 14) + ((l >> 3) << 7) + (l & 7)] = s_out[l * 193 + c];
    }
}

extern "C" void kernel_launch(void* const* d_in, const int* in_sizes, int n_in,
                              void* d_out, int out_size, void* d_ws, size_t ws_size,
                              hipStream_t stream) {
    const float* xrgb  = (const float*)d_in[0];
    const float* xsar  = (const float*)d_in[1];
    const float* gamma = (const float*)d_in[2];
    const float* beta  = (const float*)d_in[3];
    const float* ln1w  = (const float*)d_in[4];
    const float* ln1b  = (const float*)d_in[5];
    const float* ln2w  = (const float*)d_in[6];
    const float* ln2b  = (const float*)d_in[7];
    const float* qkvw  = (const float*)d_in[8];
    const float* qkvb  = (const float*)d_in[9];
    const float* apw   = (const float*)d_in[10];
    const float* apb   = (const float*)d_in[11];
    const float* relb  = (const float*)d_in[12];
    const float* qw    = (const float*)d_in[13];
    const float* kvw   = (const float*)d_in[14];
    const float* cpw   = (const float*)d_in[15];
    const float* cpb   = (const float*)d_in[16];
    const float* w1    = (const float*)d_in[17];
    const float* w2    = (const float*)d_in[18];

    float* A = (float*)d_ws;               // 25165824 floats
    float* B = A + 25165824;               // 25165824 floats (ws needs >= 201.4 MB)
    float* out = (float*)d_out;

    hipLaunchKernelGGL(k1_prep, dim3(NWIN), dim3(TPB), 0, stream, xrgb, gamma, beta, ln1w, ln1b, A);
    hipLaunchKernelGGL(k2_self, dim3(NWIN), dim3(TPB), 0, stream,
                       A, xrgb, qkvw, qkvb, apw, apb, relb, ln1w, ln1b, gamma, beta, B);
    hipLaunchKernelGGL(k3_cross, dim3(NWIN), dim3(TPB), 0, stream,
                       A, xsar, qw, kvw, cpw, cpb, ln2w, ln2b, gamma, beta, B);
    hipLaunchKernelGGL(k4_ffn, dim3(NWIN), dim3(TPB), 0, stream, A, B, w1, w2, out);
}

// Round 2
// 2260.616 us; speedup vs baseline: 4.6679x; 4.6679x over previous
//
#include <hip/hip_runtime.h>
#include <math.h>

// FusionRestormerBlock — bf16 MFMA version.
// Tokenized layout: row = wid*64 + l (l = hi*8+wi), 192 channels contiguous.
// ws: bf16 padded weights (1.33 MB) + qkv bias padded + Ag/Xg/Sg bf16 (3 x 50.3 MB) = 152 MB.
// MFMA 16x16x32 bf16: A-frag A[m=lane&15][k=(lane>>4)*8+j], B-frag B[k][n=lane&15] (k contiguous per lane),
// C/D: col=lane&15, row=(lane>>4)*4+reg.

#define TPB 256
#define NWIN 2048
#define SCALEF 0.20412414523193154f  // 24^-0.5

typedef __attribute__((ext_vector_type(8))) short bhalf8;
typedef __attribute__((ext_vector_type(4))) float fvec4;

#define MFMA(a, b, c) __builtin_amdgcn_mfma_f32_16x16x32_bf16(a, b, c, 0, 0, 0)

__device__ __forceinline__ short f2bf(float f) {
    unsigned u = __float_as_uint(f);
    u = u + 0x7fffu + ((u >> 16) & 1u);
    return (short)(u >> 16);
}
__device__ __forceinline__ float bf2f(short s) {
    return __uint_as_float(((unsigned)(unsigned short)s) << 16);
}

// Weight region element offsets (bf16 elements)
#define W_QKV 0          // [8][96][192]  (per head: 24 Q + 8 pad | 24 K + 8 pad | 24 V + 8 pad)
#define N_QKV 147456
#define N_QC  49152      // [8][32][192]
#define N_KV  98304      // [8][64][192]
#define N_AP  36864      // [192][192]
#define N_CP  36864
#define N_W1  147456     // [768][192]
#define N_W2  147456     // [192][768]
#define W_TOT 663552

// ---------------- K0: weight prep (fp32 -> padded bf16) ----------------
__global__ __launch_bounds__(TPB) void k0_wprep(
    const float* __restrict__ qkvw, const float* __restrict__ qkvb,
    const float* __restrict__ qw, const float* __restrict__ kvw,
    const float* __restrict__ apw, const float* __restrict__ cpw,
    const float* __restrict__ w1, const float* __restrict__ w2,
    short* __restrict__ Wqkv, short* __restrict__ Wqc, short* __restrict__ Wkv,
    short* __restrict__ Wap, short* __restrict__ Wcp, short* __restrict__ W1b,
    short* __restrict__ W2b, float* __restrict__ qbp)
{
    const int tid = blockIdx.x * TPB + threadIdx.x;
    const int stride = gridDim.x * TPB;
    for (int i = tid; i < N_QKV; i += stride) {
        int h = i / (96 * 192), rem = i % (96 * 192), col = rem / 192, k = rem % 192;
        int sub = col >> 5, d = col & 31;
        float v = (d < 24) ? qkvw[(sub * 192 + h * 24 + d) * 192 + k] : 0.f;
        Wqkv[i] = f2bf(v);
    }
    for (int i = tid; i < N_QC; i += stride) {
        int h = i / (32 * 192), rem = i % (32 * 192), col = rem / 192, k = rem % 192;
        float v = (col < 24) ? qw[(h * 24 + col) * 192 + k] : 0.f;
        Wqc[i] = f2bf(v);
    }
    for (int i = tid; i < N_KV; i += stride) {
        int h = i / (64 * 192), rem = i % (64 * 192), col = rem / 192, k = rem % 192;
        int sub = col >> 5, d = col & 31;
        float v = (d < 24) ? kvw[(sub * 192 + h * 24 + d) * 192 + k] : 0.f;
        Wkv[i] = f2bf(v);
    }
    for (int i = tid; i < N_AP; i += stride) Wap[i] = f2bf(apw[i]);
    for (int i = tid; i < N_CP; i += stride) Wcp[i] = f2bf(cpw[i]);
    for (int i = tid; i < N_W1; i += stride) W1b[i] = f2bf(w1[i]);
    for (int i = tid; i < N_W2; i += stride) W2b[i] = f2bf(w2[i]);
    for (int i = tid; i < 768; i += stride) {
        int h = i / 96, col = i % 96, sub = col >> 5, d = col & 31;
        qbp[i] = (d < 24) ? qkvb[sub * 192 + h * 24 + d] : 0.f;
    }
}

// ---------------- K1: tokenize + cln1 ----------------
__global__ __launch_bounds__(TPB) void k1_prep(
    const float* __restrict__ xrgb, const float* __restrict__ xsar,
    const float* __restrict__ gamma, const float* __restrict__ beta,
    const float* __restrict__ ln1w, const float* __restrict__ ln1b,
    short* __restrict__ Ag, short* __restrict__ Xg, short* __restrict__ Sg)
{
    __shared__ float s_x[64 * 193];
    __shared__ float s_mu[64], s_rs[64];
    const int tid = threadIdx.x;
    const int wid = blockIdx.x;
    const int b = wid >> 8, hb = (wid >> 4) & 15, wb = wid & 15;
    const int xbase = ((b * 192) << 14) + ((hb * 8) << 7) + wb * 8;
    const int tok0 = wid * 12288;

    for (int idx = tid; idx < 12288; idx += TPB) {
        int c = idx >> 6, l = idx & 63;
        s_x[l * 193 + c] = xrgb[xbase + (c << 14) + ((l >> 3) << 7) + (l & 7)];
    }
    __syncthreads();
    {
        int t = tid >> 2, q4 = tid & 3;
        float sum = 0.f, sq = 0.f;
        for (int j = 0; j < 48; j++) {
            float v = s_x[t * 193 + q4 * 48 + j];
            sum += v; sq += v * v;
        }
        sum += __shfl_xor(sum, 1); sum += __shfl_xor(sum, 2);
        sq  += __shfl_xor(sq, 1);  sq  += __shfl_xor(sq, 2);
        float mu = sum * (1.f / 192.f);
        float var = sq * (1.f / 192.f) - mu * mu;
        if (q4 == 0) { s_mu[t] = mu; s_rs[t] = rsqrtf(var + 1e-6f); }
    }
    __syncthreads();
    for (int idx = tid; idx < 12288; idx += TPB) {
        int t = idx / 192, c = idx - t * 192;
        float x = s_x[t * 193 + c];
        Xg[tok0 + idx] = f2bf(x);
        float xn = (x - s_mu[t]) * s_rs[t];
        Ag[tok0 + idx] = f2bf((xn * ln1w[c] + ln1b[c]) * gamma[b * 192 + c] + beta[b * 192 + c]);
    }
    __syncthreads();
    for (int idx = tid; idx < 12288; idx += TPB) {
        int c = idx >> 6, l = idx & 63;
        s_x[l * 193 + c] = xsar[xbase + (c << 14) + ((l >> 3) << 7) + (l & 7)];
    }
    __syncthreads();
    for (int idx = tid; idx < 12288; idx += TPB) {
        int t = idx / 192, c = idx - t * 192;
        Sg[tok0 + idx] = f2bf(s_x[t * 193 + c]);
    }
}

// ---------------- K2: fused self-attention (QKV + S + softmax + PV + proj + residual + cln1) ----------------
__global__ __launch_bounds__(TPB) void k2_self(
    short* __restrict__ Ag, short* __restrict__ Xg,
    const short* __restrict__ Wqkv, const float* __restrict__ qbp,
    const short* __restrict__ Wap, const float* __restrict__ apb,
    const float* __restrict__ relb,
    const float* __restrict__ ln1w, const float* __restrict__ ln1b,
    const float* __restrict__ gamma, const float* __restrict__ beta)
{
    __shared__ short s_o[12800];   // O, 64 x 200 (192 cols used)
    __shared__ short s_q[2560];    // 64 x 40 (32 cols used, zero-padded d 24..31)
    __shared__ short s_k[2560];
    __shared__ short s_vt[2304];   // 32 x 72 (V transposed: [d][token])
    __shared__ short s_p[4608];    // 64 x 72 (P row-major)
    __shared__ short s_rb[1800];   // rel bias bf16

    const int tid = threadIdx.x;
    const int wid = blockIdx.x;
    const int b = wid >> 8;
    const int mt = tid >> 6;          // wave = M-tile
    const int lane = tid & 63;
    const int g = lane >> 4;
    const int l16 = lane & 15;
    const int tok0 = wid * 12288;
    const int rowA = mt * 16 + l16;   // A-frag row (token)
    const int qrow = mt * 16 + g * 4; // C/D row base

    for (int i = tid; i < 1800; i += TPB) s_rb[i] = f2bf(relb[i]);

    const fvec4 z4 = {0.f, 0.f, 0.f, 0.f};

    for (int h = 0; h < 8; h++) {
        // ---- QKV GEMM: M=64 N=96(padded) K=192 ----
        fvec4 acc[6];
#pragma unroll
        for (int i = 0; i < 6; i++) acc[i] = z4;
        const short* wh = Wqkv + h * (96 * 192);
#pragma unroll
        for (int kt = 0; kt < 6; kt++) {
            bhalf8 af = *(const bhalf8*)&Ag[tok0 + rowA * 192 + kt * 32 + g * 8];
#pragma unroll
            for (int nt = 0; nt < 6; nt++) {
                bhalf8 bf = *(const bhalf8*)&wh[(nt * 16 + l16) * 192 + kt * 32 + g * 8];
                acc[nt] = MFMA(af, bf, acc[nt]);
            }
        }
        __syncthreads();  // prior head's S/PV readers done before overwriting s_q/s_k/s_vt
#pragma unroll
        for (int nt = 0; nt < 6; nt++) {
            float bq = qbp[h * 96 + nt * 16 + l16];
            int d = (nt & 1) * 16 + l16;
#pragma unroll
            for (int r = 0; r < 4; r++) {
                int tok = qrow + r;
                short bv = f2bf(acc[nt][r] + bq);
                if (nt < 2)      s_q[tok * 40 + d] = bv;
                else if (nt < 4) s_k[tok * 40 + d] = bv;
                else             s_vt[d * 72 + tok] = bv;
            }
        }
        __syncthreads();
        // ---- S = Q K^T (K=32 padded, pads are zero) ----
        fvec4 sacc[4];
        {
            bhalf8 qf = *(const bhalf8*)&s_q[rowA * 40 + g * 8];
#pragma unroll
            for (int nt = 0; nt < 4; nt++) {
                bhalf8 kf = *(const bhalf8*)&s_k[(nt * 16 + l16) * 40 + g * 8];
                sacc[nt] = MFMA(qf, kf, z4);
            }
        }
        // ---- scale + rel bias + softmax (rows qrow..qrow+3) ----
        float sv[4][4];
        const int n0 = l16;
#pragma unroll
        for (int nt = 0; nt < 4; nt++) {
            int n = nt * 16 + n0, ki = n >> 3, kj = n & 7;
#pragma unroll
            for (int r = 0; r < 4; r++) {
                int qq = qrow + r, qi = qq >> 3, qj = qq & 7;
                int ridx = (qi - ki + 7) * 15 + (qj - kj + 7);
                sv[nt][r] = sacc[nt][r] * SCALEF + bf2f(s_rb[ridx * 8 + h]);
            }
        }
#pragma unroll
        for (int r = 0; r < 4; r++) {
            float m = fmaxf(fmaxf(sv[0][r], sv[1][r]), fmaxf(sv[2][r], sv[3][r]));
            m = fmaxf(m, __shfl_xor(m, 1)); m = fmaxf(m, __shfl_xor(m, 2));
            m = fmaxf(m, __shfl_xor(m, 4)); m = fmaxf(m, __shfl_xor(m, 8));
            float s = 0.f;
#pragma unroll
            for (int nt = 0; nt < 4; nt++) { sv[nt][r] = __expf(sv[nt][r] - m); s += sv[nt][r]; }
            s += __shfl_xor(s, 1); s += __shfl_xor(s, 2);
            s += __shfl_xor(s, 4); s += __shfl_xor(s, 8);
            float inv = 1.f / s;
#pragma unroll
            for (int nt = 0; nt < 4; nt++) s_p[(qrow + r) * 72 + nt * 16 + n0] = f2bf(sv[nt][r] * inv);
        }
        // ---- O = P V  (K=64 keys; V^T in s_vt, pad d-cols are zero) ----
        fvec4 oacc[2];
        oacc[0] = z4; oacc[1] = z4;
#pragma unroll
        for (int ks = 0; ks < 2; ks++) {
            bhalf8 pf = *(const bhalf8*)&s_p[rowA * 72 + ks * 32 + g * 8];
#pragma unroll
            for (int nt = 0; nt < 2; nt++) {
                bhalf8 vf = *(const bhalf8*)&s_vt[(nt * 16 + l16) * 72 + ks * 32 + g * 8];
                oacc[nt] = MFMA(pf, vf, oacc[nt]);
            }
        }
#pragma unroll
        for (int nt = 0; nt < 2; nt++) {
            int d = nt * 16 + l16;
            if (d < 24) {
#pragma unroll
                for (int r = 0; r < 4; r++)
                    s_o[(qrow + r) * 200 + h * 24 + d] = f2bf(oacc[nt][r]);
            }
        }
    }
    // ---- proj: y = O @ apw^T  (M=64 N=192 K=192); s_o rows are wave-private ----
    fvec4 yacc[12];
#pragma unroll
    for (int i = 0; i < 12; i++) yacc[i] = z4;
#pragma unroll
    for (int kt = 0; kt < 6; kt++) {
        bhalf8 of = *(const bhalf8*)&s_o[rowA * 200 + kt * 32 + g * 8];
#pragma unroll
        for (int nt = 0; nt < 12; nt++) {
            bhalf8 wf = *(const bhalf8*)&Wap[(nt * 16 + l16) * 192 + kt * 32 + g * 8];
            yacc[nt] = MFMA(of, wf, yacc[nt]);
        }
    }
    // ---- epilogue: x1 = x_rgb + y + apb ; X=x1, A=cln1(x1) ----
    float sum[4] = {0.f, 0.f, 0.f, 0.f}, sq[4] = {0.f, 0.f, 0.f, 0.f};
#pragma unroll
    for (int nt = 0; nt < 12; nt++) {
        int col = nt * 16 + l16;
        float ap = apb[col];
#pragma unroll
        for (int r = 0; r < 4; r++) {
            int tok = qrow + r;
            float x = bf2f(Xg[tok0 + tok * 192 + col]) + yacc[nt][r] + ap;
            yacc[nt][r] = x;
            sum[r] += x; sq[r] += x * x;
        }
    }
#pragma unroll
    for (int r = 0; r < 4; r++) {
        float s1 = sum[r], s2 = sq[r];
        s1 += __shfl_xor(s1, 1); s1 += __shfl_xor(s1, 2); s1 += __shfl_xor(s1, 4); s1 += __shfl_xor(s1, 8);
        s2 += __shfl_xor(s2, 1); s2 += __shfl_xor(s2, 2); s2 += __shfl_xor(s2, 4); s2 += __shfl_xor(s2, 8);
        float mu = s1 * (1.f / 192.f);
        float var = s2 * (1.f / 192.f) - mu * mu;
        sum[r] = mu; sq[r] = rsqrtf(var + 1e-6f);
    }
#pragma unroll
    for (int nt = 0; nt < 12; nt++) {
        int col = nt * 16 + l16;
        float lw = ln1w[col], lb = ln1b[col], ga = gamma[b * 192 + col], be = beta[b * 192 + col];
#pragma unroll
        for (int r = 0; r < 4; r++) {
            int tok = qrow + r;
            float x = yacc[nt][r];
            Xg[tok0 + tok * 192 + col] = f2bf(x);
            float xn = (x - sum[r]) * sq[r];
            Ag[tok0 + tok * 192 + col] = f2bf((xn * lw + lb) * ga + be);
        }
    }
}

// ---------------- K3: fused cross-attention ----------------
__global__ __launch_bounds__(TPB) void k3_cross(
    short* __restrict__ Ag, short* __restrict__ Xg, const short* __restrict__ Sg,
    const short* __restrict__ Wqc, const short* __restrict__ Wkv,
    const short* __restrict__ Wcp, const float* __restrict__ cpb,
    const float* __restrict__ ln2w, const float* __restrict__ ln2b,
    const float* __restrict__ gamma, const float* __restrict__ beta)
{
    __shared__ short s_o[12800];
    __shared__ short s_q[2560];
    __shared__ short s_k[2560];
    __shared__ short s_vt[2304];
    __shared__ short s_p[4608];

    const int tid = threadIdx.x;
    const int wid = blockIdx.x;
    const int b = wid >> 8;
    const int mt = tid >> 6;
    const int lane = tid & 63;
    const int g = lane >> 4;
    const int l16 = lane & 15;
    const int tok0 = wid * 12288;
    const int rowA = mt * 16 + l16;
    const int qrow = mt * 16 + g * 4;
    const fvec4 z4 = {0.f, 0.f, 0.f, 0.f};

    for (int h = 0; h < 8; h++) {
        fvec4 accq[2], acckv[4];
        accq[0] = z4; accq[1] = z4;
#pragma unroll
        for (int i = 0; i < 4; i++) acckv[i] = z4;
        const short* wq = Wqc + h * (32 * 192);
        const short* wkv = Wkv + h * (64 * 192);
#pragma unroll
        for (int kt = 0; kt < 6; kt++) {
            bhalf8 af = *(const bhalf8*)&Ag[tok0 + rowA * 192 + kt * 32 + g * 8];
            bhalf8 sf = *(const bhalf8*)&Sg[tok0 + rowA * 192 + kt * 32 + g * 8];
#pragma unroll
            for (int nt = 0; nt < 2; nt++) {
                bhalf8 bf = *(const bhalf8*)&wq[(nt * 16 + l16) * 192 + kt * 32 + g * 8];
                accq[nt] = MFMA(af, bf, accq[nt]);
            }
#pragma unroll
            for (int nt = 0; nt < 4; nt++) {
                bhalf8 bf = *(const bhalf8*)&wkv[(nt * 16 + l16) * 192 + kt * 32 + g * 8];
                acckv[nt] = MFMA(sf, bf, acckv[nt]);
            }
        }
        __syncthreads();
#pragma unroll
        for (int nt = 0; nt < 2; nt++) {
            int d = nt * 16 + l16;
#pragma unroll
            for (int r = 0; r < 4; r++)
                s_q[(qrow + r) * 40 + d] = f2bf(accq[nt][r]);
        }
#pragma unroll
        for (int nt = 0; nt < 4; nt++) {
            int d = (nt & 1) * 16 + l16;
#pragma unroll
            for (int r = 0; r < 4; r++) {
                int tok = qrow + r;
                short bv = f2bf(acckv[nt][r]);
                if (nt < 2) s_k[tok * 40 + d] = bv;
                else        s_vt[d * 72 + tok] = bv;
            }
        }
        __syncthreads();
        fvec4 sacc[4];
        {
            bhalf8 qf = *(const bhalf8*)&s_q[rowA * 40 + g * 8];
#pragma unroll
            for (int nt = 0; nt < 4; nt++) {
                bhalf8 kf = *(const bhalf8*)&s_k[(nt * 16 + l16) * 40 + g * 8];
                sacc[nt] = MFMA(qf, kf, z4);
            }
        }
        float sv[4][4];
#pragma unroll
        for (int nt = 0; nt < 4; nt++)
#pragma unroll
            for (int r = 0; r < 4; r++)
                sv[nt][r] = sacc[nt][r] * SCALEF;
#pragma unroll
        for (int r = 0; r < 4; r++) {
            float m = fmaxf(fmaxf(sv[0][r], sv[1][r]), fmaxf(sv[2][r], sv[3][r]));
            m = fmaxf(m, __shfl_xor(m, 1)); m = fmaxf(m, __shfl_xor(m, 2));
            m = fmaxf(m, __shfl_xor(m, 4)); m = fmaxf(m, __shfl_xor(m, 8));
            float s = 0.f;
#pragma unroll
            for (int nt = 0; nt < 4; nt++) { sv[nt][r] = __expf(sv[nt][r] - m); s += sv[nt][r]; }
            s += __shfl_xor(s, 1); s += __shfl_xor(s, 2);
            s += __shfl_xor(s, 4); s += __shfl_xor(s, 8);
            float inv = 1.f / s;
#pragma unroll
            for (int nt = 0; nt < 4; nt++) s_p[(qrow + r) * 72 + nt * 16 + l16] = f2bf(sv[nt][r] * inv);
        }
        fvec4 oacc[2];
        oacc[0] = z4; oacc[1] = z4;
#pragma unroll
        for (int ks = 0; ks < 2; ks++) {
            bhalf8 pf = *(const bhalf8*)&s_p[rowA * 72 + ks * 32 + g * 8];
#pragma unroll
            for (int nt = 0; nt < 2; nt++) {
                bhalf8 vf = *(const bhalf8*)&s_vt[(nt * 16 + l16) * 72 + ks * 32 + g * 8];
                oacc[nt] = MFMA(pf, vf, oacc[nt]);
            }
        }
#pragma unroll
        for (int nt = 0; nt < 2; nt++) {
            int d = nt * 16 + l16;
            if (d < 24) {
#pragma unroll
                for (int r = 0; r < 4; r++)
                    s_o[(qrow + r) * 200 + h * 24 + d] = f2bf(oacc[nt][r]);
            }
        }
    }
    fvec4 yacc[12];
#pragma unroll
    for (int i = 0; i < 12; i++) yacc[i] = z4;
#pragma unroll
    for (int kt = 0; kt < 6; kt++) {
        bhalf8 of = *(const bhalf8*)&s_o[rowA * 200 + kt * 32 + g * 8];
#pragma unroll
        for (int nt = 0; nt < 12; nt++) {
            bhalf8 wf = *(const bhalf8*)&Wcp[(nt * 16 + l16) * 192 + kt * 32 + g * 8];
            yacc[nt] = MFMA(of, wf, yacc[nt]);
        }
    }
    float sum[4] = {0.f, 0.f, 0.f, 0.f}, sq[4] = {0.f, 0.f, 0.f, 0.f};
#pragma unroll
    for (int nt = 0; nt < 12; nt++) {
        int col = nt * 16 + l16;
        float cp = cpb[col];
#pragma unroll
        for (int r = 0; r < 4; r++) {
            int tok = qrow + r;
            float x = bf2f(Xg[tok0 + tok * 192 + col]) + yacc[nt][r] + cp;
            yacc[nt][r] = x;
            sum[r] += x; sq[r] += x * x;
        }
    }
#pragma unroll
    for (int r = 0; r < 4; r++) {
        float s1 = sum[r], s2 = sq[r];
        s1 += __shfl_xor(s1, 1); s1 += __shfl_xor(s1, 2); s1 += __shfl_xor(s1, 4); s1 += __shfl_xor(s1, 8);
        s2 += __shfl_xor(s2, 1); s2 += __shfl_xor(s2, 2); s2 += __shfl_xor(s2, 4); s2 += __shfl_xor(s2, 8);
        float mu = s1 * (1.f / 192.f);
        float var = s2 * (1.f / 192.f) - mu * mu;
        sum[r] = mu; sq[r] = rsqrtf(var + 1e-6f);
    }
#pragma unroll
    for (int nt = 0; nt < 12; nt++) {
        int col = nt * 16 + l16;
        float lw = ln2w[col], lb = ln2b[col], ga = gamma[b * 192 + col], be = beta[b * 192 + col];
#pragma unroll
        for (int r = 0; r < 4; r++) {
            int tok = qrow + r;
            float x = yacc[nt][r];
            Xg[tok0 + tok * 192 + col] = f2bf(x);
            float xn = (x - sum[r]) * sq[r];
            Ag[tok0 + tok * 192 + col] = f2bf((xn * lw + lb) * ga + be);
        }
    }
}

// ---------------- K4: fused FFN (GEMM-GELU-GEMM) + residual, scatter to NCHW ----------------
__global__ __launch_bounds__(TPB) void k4_ffn(
    const short* __restrict__ Ag, const short* __restrict__ Xg,
    const short* __restrict__ W1b, const short* __restrict__ W2b,
    float* __restrict__ out)
{
    __shared__ short s_h[64 * 136];   // hidden chunk (128 cols), wave-private rows
    __shared__ short s_out[12800];

    const int tid = threadIdx.x;
    const int wid = blockIdx.x;
    const int b = wid >> 8, hb = (wid >> 4) & 15, wb = wid & 15;
    const int xbase = ((b * 192) << 14) + ((hb * 8) << 7) + wb * 8;
    const int mt = tid >> 6;
    const int lane = tid & 63;
    const int g = lane >> 4;
    const int l16 = lane & 15;
    const int tok0 = wid * 12288;
    const int rowA = mt * 16 + l16;
    const int qrow = mt * 16 + g * 4;
    const fvec4 z4 = {0.f, 0.f, 0.f, 0.f};

    fvec4 yacc[12];
#pragma unroll
    for (int i = 0; i < 12; i++) yacc[i] = z4;

    for (int chunk = 0; chunk < 6; chunk++) {
        fvec4 hacc[8];
#pragma unroll
        for (int i = 0; i < 8; i++) hacc[i] = z4;
#pragma unroll
        for (int kt = 0; kt < 6; kt++) {
            bhalf8 af = *(const bhalf8*)&Ag[tok0 + rowA * 192 + kt * 32 + g * 8];
#pragma unroll
            for (int nt = 0; nt < 8; nt++) {
                bhalf8 wf = *(const bhalf8*)&W1b[(chunk * 128 + nt * 16 + l16) * 192 + kt * 32 + g * 8];
                hacc[nt] = MFMA(af, wf, hacc[nt]);
            }
        }
#pragma unroll
        for (int nt = 0; nt < 8; nt++) {
            int cc = nt * 16 + l16;
#pragma unroll
            for (int r = 0; r < 4; r++) {
                float x = hacc[nt][r];
                float gl = 0.5f * x * (1.f + erff(x * 0.70710678118654752f));
                s_h[(qrow + r) * 136 + cc] = f2bf(gl);
            }
        }
#pragma unroll
        for (int ks = 0; ks < 4; ks++) {
            bhalf8 hf = *(const bhalf8*)&s_h[rowA * 136 + ks * 32 + g * 8];
#pragma unroll
            for (int nt = 0; nt < 12; nt++) {
                bhalf8 wf = *(const bhalf8*)&W2b[(nt * 16 + l16) * 768 + chunk * 128 + ks * 32 + g * 8];
                yacc[nt] = MFMA(hf, wf, yacc[nt]);
            }
        }
    }
#pragma unroll
    for (int nt = 0; nt < 12; nt++) {
        int col = nt * 16 + l16;
#pragma unroll
        for (int r = 0; r < 4; r++) {
            int tok = qrow + r;
            float v = bf2f(Xg[tok0 + tok * 192 + col]) + yacc[nt][r];
            s_out[tok * 200 + col] = f2bf(v);
        }
    }
    __syncthreads();
    for (int idx = tid; idx < 12288; idx += TPB) {
        int c = idx >> 6, l = idx & 63;
        out[xbase + (c << 14) + ((l >> 3) << 7) + (l & 7)] = bf2f(s_out[l * 200 + c]);
    }
}

extern "C" void kernel_launch(void* const* d_in, const int* in_sizes, int n_in,
                              void* d_out, int out_size, void* d_ws, size_t ws_size,
                              hipStream_t stream) {
    const float* xrgb  = (const float*)d_in[0];
    const float* xsar  = (const float*)d_in[1];
    const float* gamma = (const float*)d_in[2];
    const float* beta  = (const float*)d_in[3];
    const float* ln1w  = (const float*)d_in[4];
    const float* ln1b  = (const float*)d_in[5];
    const float* ln2w  = (const float*)d_in[6];
    const float* ln2b  = (const float*)d_in[7];
    const float* qkvw  = (const float*)d_in[8];
    const float* qkvb  = (const float*)d_in[9];
    const float* apw   = (const float*)d_in[10];
    const float* apb   = (const float*)d_in[11];
    const float* relb  = (const float*)d_in[12];
    const float* qw    = (const float*)d_in[13];
    const float* kvw   = (const float*)d_in[14];
    const float* cpw   = (const float*)d_in[15];
    const float* cpb   = (const float*)d_in[16];
    const float* w1    = (const float*)d_in[17];
    const float* w2    = (const float*)d_in[18];

    char* base = (char*)d_ws;
    short* Wqkv = (short*)base;
    short* Wqc  = Wqkv + N_QKV;
    short* Wkv  = Wqc + N_QC;
    short* Wap  = Wkv + N_KV;
    short* Wcp  = Wap + N_AP;
    short* W1b  = Wcp + N_CP;
    short* W2b  = W1b + N_W1;
    float* qbp  = (float*)(base + (size_t)W_TOT * 2);          // 768 floats
    short* Ag   = (short*)(base + (size_t)W_TOT * 2 + 3072);   // 131072 x 192 bf16
    short* Xg   = Ag + 25165824;
    short* Sg   = Xg + 25165824;

    float* out = (float*)d_out;

    hipLaunchKernelGGL(k0_wprep, dim3(256), dim3(TPB), 0, stream,
                       qkvw, qkvb, qw, kvw, apw, cpw, w1, w2,
                       Wqkv, Wqc, Wkv, Wap, Wcp, W1b, W2b, qbp);
    hipLaunchKernelGGL(k1_prep, dim3(NWIN), dim3(TPB), 0, stream,
                       xrgb, xsar, gamma, beta, ln1w, ln1b, Ag, Xg, Sg);
    hipLaunchKernelGGL(k2_self, dim3(NWIN), dim3(TPB), 0, stream,
                       Ag, Xg, Wqkv, qbp, Wap, apb, relb, ln1w, ln1b, gamma, beta);
    hipLaunchKernelGGL(k3_cross, dim3(NWIN), dim3(TPB), 0, stream,
                       Ag, Xg, Sg, Wqc, Wkv, Wcp, cpb, ln2w, ln2b, gamma, beta);
    hipLaunchKernelGGL(k4_ffn, dim3(NWIN), dim3(TPB), 0, stream,
                       Ag, Xg, W1b, W2b, out);
}

// Round 3
// 1493.825 us; speedup vs baseline: 7.0640x; 1.5133x over previous
//
#include <hip/hip_runtime.h>
#include <math.h>

// FusionRestormerBlock — bf16 MFMA, fragment-ordered weights.
// Tokenized layout: row = wid*64 + l (l = hi*8+wi), 192 channels contiguous.
// Weights stored as 16(N)x32(K) tiles in MFMA B-fragment order: 512 bf16 per tile,
// element [lane*8+j] = W[n = nt*16 + (lane&15)][k = kt*32 + (lane>>4)*8 + j]
// -> B-frag load is base + tile*1024B + lane*16B, fully coalesced.
// MFMA 16x16x32 bf16 C/D: col=lane&15, row=(lane>>4)*4+reg.

#define TPB 256
#define NWIN 2048
#define SCALEF 0.20412414523193154f  // 24^-0.5

typedef __attribute__((ext_vector_type(8))) short bhalf8;
typedef __attribute__((ext_vector_type(4))) float fvec4;

#define MFMA(a, b, c) __builtin_amdgcn_mfma_f32_16x16x32_bf16(a, b, c, 0, 0, 0)

__device__ __forceinline__ short f2bf(float f) {
    unsigned u = __float_as_uint(f);
    u = u + 0x7fffu + ((u >> 16) & 1u);
    return (short)(u >> 16);
}
__device__ __forceinline__ float bf2f(short s) {
    return __uint_as_float(((unsigned)(unsigned short)s) << 16);
}

// Weight region element counts (bf16 elements), all tile-packed
#define N_QKV 147456     // 8 heads x (6 nt x 6 kt) tiles
#define N_QC  49152      // 8 x (2 x 6)
#define N_KV  98304      // 8 x (4 x 6)
#define N_AP  36864      // 12 x 6
#define N_CP  36864
#define N_W1  147456     // 48 x 6
#define N_W2  147456     // 12 nt x 24 ks
#define W_TOT 663552

// ---------------- K0: weight prep (fp32 -> padded bf16, fragment-tile order) ----------------
__global__ __launch_bounds__(TPB) void k0_wprep(
    const float* __restrict__ qkvw, const float* __restrict__ qkvb,
    const float* __restrict__ qw, const float* __restrict__ kvw,
    const float* __restrict__ apw, const float* __restrict__ cpw,
    const float* __restrict__ w1, const float* __restrict__ w2,
    short* __restrict__ Wqkv, short* __restrict__ Wqc, short* __restrict__ Wkv,
    short* __restrict__ Wap, short* __restrict__ Wcp, short* __restrict__ W1b,
    short* __restrict__ W2b, float* __restrict__ qbp)
{
    const int tid = blockIdx.x * TPB + threadIdx.x;
    const int stride = gridDim.x * TPB;
    for (int i = tid; i < N_QKV; i += stride) {
        int tile = i >> 9, pos = i & 511;
        int lane = pos >> 3, j = pos & 7, l16 = lane & 15, g = lane >> 4;
        int h = tile / 36, t2 = tile % 36, nt = t2 / 6, kt = t2 % 6;
        int col = nt * 16 + l16, sub = col >> 5, d = col & 31;
        int k = kt * 32 + g * 8 + j;
        float v = (d < 24) ? qkvw[(sub * 192 + h * 24 + d) * 192 + k] : 0.f;
        Wqkv[i] = f2bf(v);
    }
    for (int i = tid; i < N_QC; i += stride) {
        int tile = i >> 9, pos = i & 511;
        int lane = pos >> 3, j = pos & 7, l16 = lane & 15, g = lane >> 4;
        int h = tile / 12, t2 = tile % 12, nt = t2 / 6, kt = t2 % 6;
        int col = nt * 16 + l16;
        int k = kt * 32 + g * 8 + j;
        float v = (col < 24) ? qw[(h * 24 + col) * 192 + k] : 0.f;
        Wqc[i] = f2bf(v);
    }
    for (int i = tid; i < N_KV; i += stride) {
        int tile = i >> 9, pos = i & 511;
        int lane = pos >> 3, j = pos & 7, l16 = lane & 15, g = lane >> 4;
        int h = tile / 24, t2 = tile % 24, nt = t2 / 6, kt = t2 % 6;
        int col = nt * 16 + l16, sub = col >> 5, d = col & 31;
        int k = kt * 32 + g * 8 + j;
        float v = (d < 24) ? kvw[(sub * 192 + h * 24 + d) * 192 + k] : 0.f;
        Wkv[i] = f2bf(v);
    }
    for (int i = tid; i < N_AP; i += stride) {
        int tile = i >> 9, pos = i & 511;
        int lane = pos >> 3, j = pos & 7, l16 = lane & 15, g = lane >> 4;
        int nt = tile / 6, kt = tile % 6;
        int n = nt * 16 + l16, k = kt * 32 + g * 8 + j;
        Wap[i] = f2bf(apw[n * 192 + k]);
    }
    for (int i = tid; i < N_CP; i += stride) {
        int tile = i >> 9, pos = i & 511;
        int lane = pos >> 3, j = pos & 7, l16 = lane & 15, g = lane >> 4;
        int nt = tile / 6, kt = tile % 6;
        int n = nt * 16 + l16, k = kt * 32 + g * 8 + j;
        Wcp[i] = f2bf(cpw[n * 192 + k]);
    }
    for (int i = tid; i < N_W1; i += stride) {
        int tile = i >> 9, pos = i & 511;
        int lane = pos >> 3, j = pos & 7, l16 = lane & 15, g = lane >> 4;
        int nt = tile / 6, kt = tile % 6;
        int n = nt * 16 + l16, k = kt * 32 + g * 8 + j;
        W1b[i] = f2bf(w1[n * 192 + k]);
    }
    for (int i = tid; i < N_W2; i += stride) {
        int tile = i >> 9, pos = i & 511;
        int lane = pos >> 3, j = pos & 7, l16 = lane & 15, g = lane >> 4;
        int nt = tile / 24, ks = tile % 24;
        int n = nt * 16 + l16, k = ks * 32 + g * 8 + j;
        W2b[i] = f2bf(w2[n * 768 + k]);
    }
    for (int i = tid; i < 768; i += stride) {
        int h = i / 96, col = i % 96, sub = col >> 5, d = col & 31;
        qbp[i] = (d < 24) ? qkvb[sub * 192 + h * 24 + d] : 0.f;
    }
}

// ---------------- K1: tokenize + cln1 ----------------
__global__ __launch_bounds__(TPB) void k1_prep(
    const float* __restrict__ xrgb, const float* __restrict__ xsar,
    const float* __restrict__ gamma, const float* __restrict__ beta,
    const float* __restrict__ ln1w, const float* __restrict__ ln1b,
    short* __restrict__ Ag, short* __restrict__ Xg, short* __restrict__ Sg)
{
    __shared__ float s_x[64 * 193];
    __shared__ float s_mu[64], s_rs[64];
    const int tid = threadIdx.x;
    const int wid = blockIdx.x;
    const int b = wid >> 8, hb = (wid >> 4) & 15, wb = wid & 15;
    const int xbase = ((b * 192) << 14) + ((hb * 8) << 7) + wb * 8;
    const int tok0 = wid * 12288;

    for (int idx = tid; idx < 12288; idx += TPB) {
        int c = idx >> 6, l = idx & 63;
        s_x[l * 193 + c] = xrgb[xbase + (c << 14) + ((l >> 3) << 7) + (l & 7)];
    }
    __syncthreads();
    {
        int t = tid >> 2, q4 = tid & 3;
        float sum = 0.f, sq = 0.f;
        for (int j = 0; j < 48; j++) {
            float v = s_x[t * 193 + q4 * 48 + j];
            sum += v; sq += v * v;
        }
        sum += __shfl_xor(sum, 1); sum += __shfl_xor(sum, 2);
        sq  += __shfl_xor(sq, 1);  sq  += __shfl_xor(sq, 2);
        float mu = sum * (1.f / 192.f);
        float var = sq * (1.f / 192.f) - mu * mu;
        if (q4 == 0) { s_mu[t] = mu; s_rs[t] = rsqrtf(var + 1e-6f); }
    }
    __syncthreads();
    for (int idx = tid; idx < 12288; idx += TPB) {
        int t = idx / 192, c = idx - t * 192;
        float x = s_x[t * 193 + c];
        Xg[tok0 + idx] = f2bf(x);
        float xn = (x - s_mu[t]) * s_rs[t];
        Ag[tok0 + idx] = f2bf((xn * ln1w[c] + ln1b[c]) * gamma[b * 192 + c] + beta[b * 192 + c]);
    }
    __syncthreads();
    for (int idx = tid; idx < 12288; idx += TPB) {
        int c = idx >> 6, l = idx & 63;
        s_x[l * 193 + c] = xsar[xbase + (c << 14) + ((l >> 3) << 7) + (l & 7)];
    }
    __syncthreads();
    for (int idx = tid; idx < 12288; idx += TPB) {
        int t = idx / 192, c = idx - t * 192;
        Sg[tok0 + idx] = f2bf(s_x[t * 193 + c]);
    }
}

// ---------------- K2: fused self-attention ----------------
__global__ __launch_bounds__(TPB) void k2_self(
    short* __restrict__ Ag, short* __restrict__ Xg,
    const short* __restrict__ Wqkv, const float* __restrict__ qbp,
    const short* __restrict__ Wap, const float* __restrict__ apb,
    const float* __restrict__ relb,
    const float* __restrict__ ln1w, const float* __restrict__ ln1b,
    const float* __restrict__ gamma, const float* __restrict__ beta)
{
    __shared__ short s_o[12800];   // O, 64 x 200 (192 cols used)
    __shared__ short s_q[2560];    // 64 x 40 (32 cols used, zero-padded d 24..31)
    __shared__ short s_k[2560];
    __shared__ short s_vt[2304];   // 32 x 72 (V transposed: [d][token])
    __shared__ short s_p[4608];    // 64 x 72 (P row-major)
    __shared__ short s_rb[1800];   // rel bias bf16

    const int tid = threadIdx.x;
    const int wid = blockIdx.x;
    const int b = wid >> 8;
    const int mt = tid >> 6;
    const int lane = tid & 63;
    const int g = lane >> 4;
    const int l16 = lane & 15;
    const int fo = lane << 3;         // fragment-tile offset (elements)
    const int tok0 = wid * 12288;
    const int rowA = mt * 16 + l16;
    const int qrow = mt * 16 + g * 4;

    for (int i = tid; i < 1800; i += TPB) s_rb[i] = f2bf(relb[i]);

    const fvec4 z4 = {0.f, 0.f, 0.f, 0.f};

    for (int h = 0; h < 8; h++) {
        // ---- QKV GEMM: M=64 N=96(padded) K=192 ----
        fvec4 acc[6];
#pragma unroll
        for (int i = 0; i < 6; i++) acc[i] = z4;
#pragma unroll
        for (int kt = 0; kt < 6; kt++) {
            bhalf8 af = *(const bhalf8*)&Ag[tok0 + rowA * 192 + kt * 32 + g * 8];
#pragma unroll
            for (int nt = 0; nt < 6; nt++) {
                bhalf8 bf = *(const bhalf8*)&Wqkv[((h * 36 + nt * 6 + kt) << 9) + fo];
                acc[nt] = MFMA(af, bf, acc[nt]);
            }
        }
        __syncthreads();  // prior head's S/PV readers done before overwriting s_q/s_k/s_vt
#pragma unroll
        for (int nt = 0; nt < 6; nt++) {
            float bq = qbp[h * 96 + nt * 16 + l16];
            int d = (nt & 1) * 16 + l16;
#pragma unroll
            for (int r = 0; r < 4; r++) {
                int tok = qrow + r;
                short bv = f2bf(acc[nt][r] + bq);
                if (nt < 2)      s_q[tok * 40 + d] = bv;
                else if (nt < 4) s_k[tok * 40 + d] = bv;
                else             s_vt[d * 72 + tok] = bv;
            }
        }
        __syncthreads();
        // ---- S = Q K^T (K=32 padded, pads are zero) ----
        fvec4 sacc[4];
        {
            bhalf8 qf = *(const bhalf8*)&s_q[rowA * 40 + g * 8];
#pragma unroll
            for (int nt = 0; nt < 4; nt++) {
                bhalf8 kf = *(const bhalf8*)&s_k[(nt * 16 + l16) * 40 + g * 8];
                sacc[nt] = MFMA(qf, kf, z4);
            }
        }
        // ---- scale + rel bias + softmax ----
        float sv[4][4];
#pragma unroll
        for (int nt = 0; nt < 4; nt++) {
            int n = nt * 16 + l16, ki = n >> 3, kj = n & 7;
#pragma unroll
            for (int r = 0; r < 4; r++) {
                int qq = qrow + r, qi = qq >> 3, qj = qq & 7;
                int ridx = (qi - ki + 7) * 15 + (qj - kj + 7);
                sv[nt][r] = sacc[nt][r] * SCALEF + bf2f(s_rb[ridx * 8 + h]);
            }
        }
#pragma unroll
        for (int r = 0; r < 4; r++) {
            float m = fmaxf(fmaxf(sv[0][r], sv[1][r]), fmaxf(sv[2][r], sv[3][r]));
            m = fmaxf(m, __shfl_xor(m, 1)); m = fmaxf(m, __shfl_xor(m, 2));
            m = fmaxf(m, __shfl_xor(m, 4)); m = fmaxf(m, __shfl_xor(m, 8));
            float s = 0.f;
#pragma unroll
            for (int nt = 0; nt < 4; nt++) { sv[nt][r] = __expf(sv[nt][r] - m); s += sv[nt][r]; }
            s += __shfl_xor(s, 1); s += __shfl_xor(s, 2);
            s += __shfl_xor(s, 4); s += __shfl_xor(s, 8);
            float inv = 1.f / s;
#pragma unroll
            for (int nt = 0; nt < 4; nt++) s_p[(qrow + r) * 72 + nt * 16 + l16] = f2bf(sv[nt][r] * inv);
        }
        // ---- O = P V ----
        fvec4 oacc[2];
        oacc[0] = z4; oacc[1] = z4;
#pragma unroll
        for (int ks = 0; ks < 2; ks++) {
            bhalf8 pf = *(const bhalf8*)&s_p[rowA * 72 + ks * 32 + g * 8];
#pragma unroll
            for (int nt = 0; nt < 2; nt++) {
                bhalf8 vf = *(const bhalf8*)&s_vt[(nt * 16 + l16) * 72 + ks * 32 + g * 8];
                oacc[nt] = MFMA(pf, vf, oacc[nt]);
            }
        }
#pragma unroll
        for (int nt = 0; nt < 2; nt++) {
            int d = nt * 16 + l16;
            if (d < 24) {
#pragma unroll
                for (int r = 0; r < 4; r++)
                    s_o[(qrow + r) * 200 + h * 24 + d] = f2bf(oacc[nt][r]);
            }
        }
    }
    // ---- proj: y = O @ apw^T ----
    fvec4 yacc[12];
#pragma unroll
    for (int i = 0; i < 12; i++) yacc[i] = z4;
#pragma unroll
    for (int kt = 0; kt < 6; kt++) {
        bhalf8 of = *(const bhalf8*)&s_o[rowA * 200 + kt * 32 + g * 8];
#pragma unroll
        for (int nt = 0; nt < 12; nt++) {
            bhalf8 wf = *(const bhalf8*)&Wap[((nt * 6 + kt) << 9) + fo];
            yacc[nt] = MFMA(of, wf, yacc[nt]);
        }
    }
    // ---- epilogue: x1 = x_rgb + y + apb ; X=x1, A=cln1(x1) ----
    float sum[4] = {0.f, 0.f, 0.f, 0.f}, sq[4] = {0.f, 0.f, 0.f, 0.f};
#pragma unroll
    for (int nt = 0; nt < 12; nt++) {
        int col = nt * 16 + l16;
        float ap = apb[col];
#pragma unroll
        for (int r = 0; r < 4; r++) {
            int tok = qrow + r;
            float x = bf2f(Xg[tok0 + tok * 192 + col]) + yacc[nt][r] + ap;
            yacc[nt][r] = x;
            sum[r] += x; sq[r] += x * x;
        }
    }
#pragma unroll
    for (int r = 0; r < 4; r++) {
        float s1 = sum[r], s2 = sq[r];
        s1 += __shfl_xor(s1, 1); s1 += __shfl_xor(s1, 2); s1 += __shfl_xor(s1, 4); s1 += __shfl_xor(s1, 8);
        s2 += __shfl_xor(s2, 1); s2 += __shfl_xor(s2, 2); s2 += __shfl_xor(s2, 4); s2 += __shfl_xor(s2, 8);
        float mu = s1 * (1.f / 192.f);
        float var = s2 * (1.f / 192.f) - mu * mu;
        sum[r] = mu; sq[r] = rsqrtf(var + 1e-6f);
    }
#pragma unroll
    for (int nt = 0; nt < 12; nt++) {
        int col = nt * 16 + l16;
        float lw = ln1w[col], lb = ln1b[col], ga = gamma[b * 192 + col], be = beta[b * 192 + col];
#pragma unroll
        for (int r = 0; r < 4; r++) {
            int tok = qrow + r;
            float x = yacc[nt][r];
            Xg[tok0 + tok * 192 + col] = f2bf(x);
            float xn = (x - sum[r]) * sq[r];
            Ag[tok0 + tok * 192 + col] = f2bf((xn * lw + lb) * ga + be);
        }
    }
}

// ---------------- K3: fused cross-attention ----------------
__global__ __launch_bounds__(TPB) void k3_cross(
    short* __restrict__ Ag, short* __restrict__ Xg, const short* __restrict__ Sg,
    const short* __restrict__ Wqc, const short* __restrict__ Wkv,
    const short* __restrict__ Wcp, const float* __restrict__ cpb,
    const float* __restrict__ ln2w, const float* __restrict__ ln2b,
    const float* __restrict__ gamma, const float* __restrict__ beta)
{
    __shared__ short s_o[12800];
    __shared__ short s_q[2560];
    __shared__ short s_k[2560];
    __shared__ short s_vt[2304];
    __shared__ short s_p[4608];

    const int tid = threadIdx.x;
    const int wid = blockIdx.x;
    const int b = wid >> 8;
    const int mt = tid >> 6;
    const int lane = tid & 63;
    const int g = lane >> 4;
    const int l16 = lane & 15;
    const int fo = lane << 3;
    const int tok0 = wid * 12288;
    const int rowA = mt * 16 + l16;
    const int qrow = mt * 16 + g * 4;
    const fvec4 z4 = {0.f, 0.f, 0.f, 0.f};

    for (int h = 0; h < 8; h++) {
        fvec4 accq[2], acckv[4];
        accq[0] = z4; accq[1] = z4;
#pragma unroll
        for (int i = 0; i < 4; i++) acckv[i] = z4;
#pragma unroll
        for (int kt = 0; kt < 6; kt++) {
            bhalf8 af = *(const bhalf8*)&Ag[tok0 + rowA * 192 + kt * 32 + g * 8];
            bhalf8 sf = *(const bhalf8*)&Sg[tok0 + rowA * 192 + kt * 32 + g * 8];
#pragma unroll
            for (int nt = 0; nt < 2; nt++) {
                bhalf8 bf = *(const bhalf8*)&Wqc[((h * 12 + nt * 6 + kt) << 9) + fo];
                accq[nt] = MFMA(af, bf, accq[nt]);
            }
#pragma unroll
            for (int nt = 0; nt < 4; nt++) {
                bhalf8 bf = *(const bhalf8*)&Wkv[((h * 24 + nt * 6 + kt) << 9) + fo];
                acckv[nt] = MFMA(sf, bf, acckv[nt]);
            }
        }
        __syncthreads();
#pragma unroll
        for (int nt = 0; nt < 2; nt++) {
            int d = nt * 16 + l16;
#pragma unroll
            for (int r = 0; r < 4; r++)
                s_q[(qrow + r) * 40 + d] = f2bf(accq[nt][r]);
        }
#pragma unroll
        for (int nt = 0; nt < 4; nt++) {
            int d = (nt & 1) * 16 + l16;
#pragma unroll
            for (int r = 0; r < 4; r++) {
                int tok = qrow + r;
                short bv = f2bf(acckv[nt][r]);
                if (nt < 2) s_k[tok * 40 + d] = bv;
                else        s_vt[d * 72 + tok] = bv;
            }
        }
        __syncthreads();
        fvec4 sacc[4];
        {
            bhalf8 qf = *(const bhalf8*)&s_q[rowA * 40 + g * 8];
#pragma unroll
            for (int nt = 0; nt < 4; nt++) {
                bhalf8 kf = *(const bhalf8*)&s_k[(nt * 16 + l16) * 40 + g * 8];
                sacc[nt] = MFMA(qf, kf, z4);
            }
        }
        float sv[4][4];
#pragma unroll
        for (int nt = 0; nt < 4; nt++)
#pragma unroll
            for (int r = 0; r < 4; r++)
                sv[nt][r] = sacc[nt][r] * SCALEF;
#pragma unroll
        for (int r = 0; r < 4; r++) {
            float m = fmaxf(fmaxf(sv[0][r], sv[1][r]), fmaxf(sv[2][r], sv[3][r]));
            m = fmaxf(m, __shfl_xor(m, 1)); m = fmaxf(m, __shfl_xor(m, 2));
            m = fmaxf(m, __shfl_xor(m, 4)); m = fmaxf(m, __shfl_xor(m, 8));
            float s = 0.f;
#pragma unroll
            for (int nt = 0; nt < 4; nt++) { sv[nt][r] = __expf(sv[nt][r] - m); s += sv[nt][r]; }
            s += __shfl_xor(s, 1); s += __shfl_xor(s, 2);
            s += __shfl_xor(s, 4); s += __shfl_xor(s, 8);
            float inv = 1.f / s;
#pragma unroll
            for (int nt = 0; nt < 4; nt++) s_p[(qrow + r) * 72 + nt * 16 + l16] = f2bf(sv[nt][r] * inv);
        }
        fvec4 oacc[2];
        oacc[0] = z4; oacc[1] = z4;
#pragma unroll
        for (int ks = 0; ks < 2; ks++) {
            bhalf8 pf = *(const bhalf8*)&s_p[rowA * 72 + ks * 32 + g * 8];
#pragma unroll
            for (int nt = 0; nt < 2; nt++) {
                bhalf8 vf = *(const bhalf8*)&s_vt[(nt * 16 + l16) * 72 + ks * 32 + g * 8];
                oacc[nt] = MFMA(pf, vf, oacc[nt]);
            }
        }
#pragma unroll
        for (int nt = 0; nt < 2; nt++) {
            int d = nt * 16 + l16;
            if (d < 24) {
#pragma unroll
                for (int r = 0; r < 4; r++)
                    s_o[(qrow + r) * 200 + h * 24 + d] = f2bf(oacc[nt][r]);
            }
        }
    }
    fvec4 yacc[12];
#pragma unroll
    for (int i = 0; i < 12; i++) yacc[i] = z4;
#pragma unroll
    for (int kt = 0; kt < 6; kt++) {
        bhalf8 of = *(const bhalf8*)&s_o[rowA * 200 + kt * 32 + g * 8];
#pragma unroll
        for (int nt = 0; nt < 12; nt++) {
            bhalf8 wf = *(const bhalf8*)&Wcp[((nt * 6 + kt) << 9) + fo];
            yacc[nt] = MFMA(of, wf, yacc[nt]);
        }
    }
    float sum[4] = {0.f, 0.f, 0.f, 0.f}, sq[4] = {0.f, 0.f, 0.f, 0.f};
#pragma unroll
    for (int nt = 0; nt < 12; nt++) {
        int col = nt * 16 + l16;
        float cp = cpb[col];
#pragma unroll
        for (int r = 0; r < 4; r++) {
            int tok = qrow + r;
            float x = bf2f(Xg[tok0 + tok * 192 + col]) + yacc[nt][r] + cp;
            yacc[nt][r] = x;
            sum[r] += x; sq[r] += x * x;
        }
    }
#pragma unroll
    for (int r = 0; r < 4; r++) {
        float s1 = sum[r], s2 = sq[r];
        s1 += __shfl_xor(s1, 1); s1 += __shfl_xor(s1, 2); s1 += __shfl_xor(s1, 4); s1 += __shfl_xor(s1, 8);
        s2 += __shfl_xor(s2, 1); s2 += __shfl_xor(s2, 2); s2 += __shfl_xor(s2, 4); s2 += __shfl_xor(s2, 8);
        float mu = s1 * (1.f / 192.f);
        float var = s2 * (1.f / 192.f) - mu * mu;
        sum[r] = mu; sq[r] = rsqrtf(var + 1e-6f);
    }
#pragma unroll
    for (int nt = 0; nt < 12; nt++) {
        int col = nt * 16 + l16;
        float lw = ln2w[col], lb = ln2b[col], ga = gamma[b * 192 + col], be = beta[b * 192 + col];
#pragma unroll
        for (int r = 0; r < 4; r++) {
            int tok = qrow + r;
            float x = yacc[nt][r];
            Xg[tok0 + tok * 192 + col] = f2bf(x);
            float xn = (x - sum[r]) * sq[r];
            Ag[tok0 + tok * 192 + col] = f2bf((xn * lw + lb) * ga + be);
        }
    }
}

// ---------------- K4: fused FFN + residual, scatter to NCHW ----------------
__global__ __launch_bounds__(TPB) void k4_ffn(
    const short* __restrict__ Ag, const short* __restrict__ Xg,
    const short* __restrict__ W1b, const short* __restrict__ W2b,
    float* __restrict__ out)
{
    __shared__ short s_buf[12800];    // union: s_h (64x136) during chunks, s_out (64x200) at end
    short* s_h = s_buf;
    short* s_out = s_buf;

    const int tid = threadIdx.x;
    const int wid = blockIdx.x;
    const int b = wid >> 8, hb = (wid >> 4) & 15, wb = wid & 15;
    const int xbase = ((b * 192) << 14) + ((hb * 8) << 7) + wb * 8;
    const int mt = tid >> 6;
    const int lane = tid & 63;
    const int g = lane >> 4;
    const int l16 = lane & 15;
    const int fo = lane << 3;
    const int tok0 = wid * 12288;
    const int rowA = mt * 16 + l16;
    const int qrow = mt * 16 + g * 4;
    const fvec4 z4 = {0.f, 0.f, 0.f, 0.f};

    fvec4 yacc[12];
#pragma unroll
    for (int i = 0; i < 12; i++) yacc[i] = z4;

    for (int chunk = 0; chunk < 6; chunk++) {
        fvec4 hacc[8];
#pragma unroll
        for (int i = 0; i < 8; i++) hacc[i] = z4;
#pragma unroll
        for (int kt = 0; kt < 6; kt++) {
            bhalf8 af = *(const bhalf8*)&Ag[tok0 + rowA * 192 + kt * 32 + g * 8];
#pragma unroll
            for (int nt = 0; nt < 8; nt++) {
                bhalf8 wf = *(const bhalf8*)&W1b[(((chunk * 8 + nt) * 6 + kt) << 9) + fo];
                hacc[nt] = MFMA(af, wf, hacc[nt]);
            }
        }
#pragma unroll
        for (int nt = 0; nt < 8; nt++) {
            int cc = nt * 16 + l16;
#pragma unroll
            for (int r = 0; r < 4; r++) {
                float x = hacc[nt][r];
                float gl = 0.5f * x * (1.f + erff(x * 0.70710678118654752f));
                s_h[(qrow + r) * 136 + cc] = f2bf(gl);
            }
        }
#pragma unroll
        for (int ks = 0; ks < 4; ks++) {
            bhalf8 hf = *(const bhalf8*)&s_h[rowA * 136 + ks * 32 + g * 8];
#pragma unroll
            for (int nt = 0; nt < 12; nt++) {
                bhalf8 wf = *(const bhalf8*)&W2b[((nt * 24 + chunk * 4 + ks) << 9) + fo];
                yacc[nt] = MFMA(hf, wf, yacc[nt]);
            }
        }
    }
    __syncthreads();  // s_h readers done before s_out overwrites (regions overlap across waves)
#pragma unroll
    for (int nt = 0; nt < 12; nt++) {
        int col = nt * 16 + l16;
#pragma unroll
        for (int r = 0; r < 4; r++) {
            int tok = qrow + r;
            float v = bf2f(Xg[tok0 + tok * 192 + col]) + yacc[nt][r];
            s_out[tok * 200 + col] = f2bf(v);
        }
    }
    __syncthreads();
    for (int idx = tid; idx < 12288; idx += TPB) {
        int c = idx >> 6, l = idx & 63;
        out[xbase + (c << 14) + ((l >> 3) << 7) + (l & 7)] = bf2f(s_out[l * 200 + c]);
    }
}

extern "C" void kernel_launch(void* const* d_in, const int* in_sizes, int n_in,
                              void* d_out, int out_size, void* d_ws, size_t ws_size,
                              hipStream_t stream) {
    const float* xrgb  = (const float*)d_in[0];
    const float* xsar  = (const float*)d_in[1];
    const float* gamma = (const float*)d_in[2];
    const float* beta  = (const float*)d_in[3];
    const float* ln1w  = (const float*)d_in[4];
    const float* ln1b  = (const float*)d_in[5];
    const float* ln2w  = (const float*)d_in[6];
    const float* ln2b  = (const float*)d_in[7];
    const float* qkvw  = (const float*)d_in[8];
    const float* qkvb  = (const float*)d_in[9];
    const float* apw   = (const float*)d_in[10];
    const float* apb   = (const float*)d_in[11];
    const float* relb  = (const float*)d_in[12];
    const float* qw    = (const float*)d_in[13];
    const float* kvw   = (const float*)d_in[14];
    const float* cpw   = (const float*)d_in[15];
    const float* cpb   = (const float*)d_in[16];
    const float* w1    = (const float*)d_in[17];
    const float* w2    = (const float*)d_in[18];

    char* base = (char*)d_ws;
    short* Wqkv = (short*)base;
    short* Wqc  = Wqkv + N_QKV;
    short* Wkv  = Wqc + N_QC;
    short* Wap  = Wkv + N_KV;
    short* Wcp  = Wap + N_AP;
    short* W1b  = Wcp + N_CP;
    short* W2b  = W1b + N_W1;
    float* qbp  = (float*)(base + (size_t)W_TOT * 2);          // 768 floats
    short* Ag   = (short*)(base + (size_t)W_TOT * 2 + 3072);   // 131072 x 192 bf16
    short* Xg   = Ag + 25165824;
    short* Sg   = Xg + 25165824;

    float* out = (float*)d_out;

    hipLaunchKernelGGL(k0_wprep, dim3(256), dim3(TPB), 0, stream,
                       qkvw, qkvb, qw, kvw, apw, cpw, w1, w2,
                       Wqkv, Wqc, Wkv, Wap, Wcp, W1b, W2b, qbp);
    hipLaunchKernelGGL(k1_prep, dim3(NWIN), dim3(TPB), 0, stream,
                       xrgb, xsar, gamma, beta, ln1w, ln1b, Ag, Xg, Sg);
    hipLaunchKernelGGL(k2_self, dim3(NWIN), dim3(TPB), 0, stream,
                       Ag, Xg, Wqkv, qbp, Wap, apb, relb, ln1w, ln1b, gamma, beta);
    hipLaunchKernelGGL(k3_cross, dim3(NWIN), dim3(TPB), 0, stream,
                       Ag, Xg, Sg, Wqc, Wkv, Wcp, cpb, ln2w, ln2b, gamma, beta);
    hipLaunchKernelGGL(k4_ffn, dim3(NWIN), dim3(TPB), 0, stream,
                       Ag, Xg, W1b, W2b, out);
}